// Round 5
// baseline (119.894 us; speedup 1.0000x reference)
//
#include <hip/hip_runtime.h>
#include <hip/hip_bf16.h>

typedef __attribute__((ext_vector_type(8))) short bf16x8;
typedef __attribute__((ext_vector_type(4))) float f32x4;

#define K_REAL 2145    // 33*65
#define NKT 34         // padded K 2176 / 64
#define DIM0 33
#define DIM1 33
#define DIM2 65
#define NROW 2048
#define OO 128

// Fragment-ordered operand layouts (pure permutation, built by prep kernels):
//   Uf  frag (m,t,wr,mi,ks,lane): idx = ((m*34+t)*8 + wr*4+mi*2+ks)*512 + lane*8
//        holds U[m*64 + wr*32 + mi*16 + (lane&15)][t*64 + ks*32 + (lane>>4)*8 + j]
//   Wtf frag (a,t,ni2,ks,lane):   idx = ((a*34+t)*16 + ni2*2+ks)*512 + lane*8
//        holds Wt_a[o = ni2*16 + (lane&15)][t*64 + ks*32 + (lane>>4)*8 + j]
// GEMM waves then issue only coalesced 1KB global_load_dwordx4 straight to VGPRs.

__device__ __forceinline__ unsigned short f2bf(float f) {
  union { float f; unsigned u; } v; v.f = f;
  unsigned r = v.u + 0x7fffu + ((v.u >> 16) & 1u);   // round-to-nearest-even
  return (unsigned short)(r >> 16);
}

// ---- Uf = frag-ordered bf16( x1[n,b]*x2[n,c] ) ----
__global__ __launch_bounds__(256) void prep_u_kernel(const float* __restrict__ x1,
                                                     const float* __restrict__ x2,
                                                     ushort* __restrict__ Uf) {
  int m = blockIdx.x;   // 0..31
  int t = blockIdx.y;   // 0..33
  int tid = threadIdx.x;
#pragma unroll
  for (int ch = 0; ch < 2; ++ch) {
    int cid = ch * 256 + tid;           // 0..511
    int f = cid >> 6;                   // wr*4 + mi*2 + ks
    int lane = cid & 63;
    int row = m * 64 + (f >> 2) * 32 + ((f >> 1) & 1) * 16 + (lane & 15);
    int kb = t * 64 + (f & 1) * 32 + (lane >> 4) * 8;
    union { ushort us[8]; uint4 v; } pk;
#pragma unroll
    for (int j = 0; j < 8; ++j) {
      int k = kb + j;
      float val = 0.f;
      if (k < K_REAL) {
        int b = k / DIM2; int c = k - b * DIM2;
        val = x1[row * DIM1 + b] * x2[row * DIM2 + c];
      }
      pk.us[j] = f2bf(val);
    }
    *(uint4*)&Uf[((size_t)(m * 34 + t) * 8 + f) * 512 + lane * 8] = pk.v;
  }
}

// ---- Wtf = frag-ordered bf16( W[a,b,c,o] ) ----
__global__ __launch_bounds__(256) void prep_wt_kernel(const float* __restrict__ W,
                                                      ushort* __restrict__ Wtf) {
  int t = blockIdx.x;   // 0..33
  int a = blockIdx.y;   // 0..32
  int tid = threadIdx.x;
#pragma unroll
  for (int ch = 0; ch < 4; ++ch) {
    int cid = ch * 256 + tid;           // 0..1023
    int f = cid >> 6;                   // ni2*2 + ks
    int lane = cid & 63;
    int o = (f >> 1) * 16 + (lane & 15);
    int kb = t * 64 + (f & 1) * 32 + (lane >> 4) * 8;
    union { ushort us[8]; uint4 v; } pk;
#pragma unroll
    for (int j = 0; j < 8; ++j) {
      int k = kb + j;
      float val = 0.f;
      if (k < K_REAL) {
        int b = k / DIM2; int c = k - b * DIM2;
        val = W[(((size_t)a * DIM1 + b) * DIM2 + c) * OO + o];
      }
      pk.us[j] = f2bf(val);
    }
    *(uint4*)&Wtf[((size_t)(a * 34 + t) * 16 + f) * 512 + lane * 8] = pk.v;
  }
}

// ---- main GEMM: zero LDS, zero drains. Operands stream global->reg in frag
//      order, double-buffered (named even/odd regs); bare s_barrier keeps the
//      4 waves lockstep for L1 sharing of the 2x-duplicated fragments. ----
__global__ __launch_bounds__(256, 3) void gemm_kernel(const ushort* __restrict__ Uf,
                                                      const ushort* __restrict__ Wtf,
                                                      const float* __restrict__ x0,
                                                      float* __restrict__ out) {
  int tid = threadIdx.x;
  int lane = tid & 63;
  int w = tid >> 6;
  int wr = w >> 1, wc = w & 1;

  // XCD-aware bijective swizzle: 1056 blocks, 132 per XCD, a-major within XCD.
  int orig = (int)blockIdx.x;
  int logical = (orig & 7) * 132 + (orig >> 3);
  int a = logical >> 5;        // 0..32
  int m = logical & 31;        // 0..31
  int n0 = m * 64;

  const ushort* Ua = Uf  + ((size_t)m * 34 * 8  + wr * 4) * 512 + (size_t)lane * 8;
  const ushort* Ub = Wtf + ((size_t)a * 34 * 16 + wc * 8) * 512 + (size_t)lane * 8;

#define LDA(V, T, MI, KS) V = *(const bf16x8*)(Ua + (size_t)(T) * 4096 + ((MI)*2 + (KS)) * 512)
#define LDB(V, T, NB, KS) V = *(const bf16x8*)(Ub + (size_t)(T) * 8192 + ((NB)*2 + (KS)) * 512)

  bf16x8 ae0, ae1, ae2, ae3, be0, be1, be2, be3, be4, be5, be6, be7;
  bf16x8 ao0, ao1, ao2, ao3, bo0, bo1, bo2, bo3, bo4, bo5, bo6, bo7;

  f32x4 acc[2][4];
#pragma unroll
  for (int mi = 0; mi < 2; ++mi)
#pragma unroll
    for (int ni = 0; ni < 4; ++ni)
      acc[mi][ni] = (f32x4){0.f, 0.f, 0.f, 0.f};

#define LOADE(T) { LDA(ae0,T,0,0); LDA(ae1,T,0,1); LDA(ae2,T,1,0); LDA(ae3,T,1,1); \
                   LDB(be0,T,0,0); LDB(be1,T,0,1); LDB(be2,T,1,0); LDB(be3,T,1,1); \
                   LDB(be4,T,2,0); LDB(be5,T,2,1); LDB(be6,T,3,0); LDB(be7,T,3,1); }
#define LOADO(T) { LDA(ao0,T,0,0); LDA(ao1,T,0,1); LDA(ao2,T,1,0); LDA(ao3,T,1,1); \
                   LDB(bo0,T,0,0); LDB(bo1,T,0,1); LDB(bo2,T,1,0); LDB(bo3,T,1,1); \
                   LDB(bo4,T,2,0); LDB(bo5,T,2,1); LDB(bo6,T,3,0); LDB(bo7,T,3,1); }

#define MFMA(A, B, C) C = __builtin_amdgcn_mfma_f32_16x16x32_bf16(A, B, C, 0, 0, 0)
#define COMP(A0,A1,A2,A3, B0,B1,B2,B3,B4,B5,B6,B7) { \
  __builtin_amdgcn_s_setprio(1); \
  MFMA(A0, B0, acc[0][0]); MFMA(A0, B2, acc[0][1]); MFMA(A0, B4, acc[0][2]); MFMA(A0, B6, acc[0][3]); \
  MFMA(A2, B0, acc[1][0]); MFMA(A2, B2, acc[1][1]); MFMA(A2, B4, acc[1][2]); MFMA(A2, B6, acc[1][3]); \
  MFMA(A1, B1, acc[0][0]); MFMA(A1, B3, acc[0][1]); MFMA(A1, B5, acc[0][2]); MFMA(A1, B7, acc[0][3]); \
  MFMA(A3, B1, acc[1][0]); MFMA(A3, B3, acc[1][1]); MFMA(A3, B5, acc[1][2]); MFMA(A3, B7, acc[1][3]); \
  __builtin_amdgcn_s_setprio(0); }

  LOADE(0);
  for (int it = 0; it < 16; ++it) {
    int t = it * 2;
    LOADO(t + 1);
    __builtin_amdgcn_s_barrier();
    COMP(ae0, ae1, ae2, ae3, be0, be1, be2, be3, be4, be5, be6, be7);
    LOADE(t + 2);
    __builtin_amdgcn_s_barrier();
    COMP(ao0, ao1, ao2, ao3, bo0, bo1, bo2, bo3, bo4, bo5, bo6, bo7);
  }
  LOADO(33);
  __builtin_amdgcn_s_barrier();
  COMP(ae0, ae1, ae2, ae3, be0, be1, be2, be3, be4, be5, be6, be7);   // t = 32
  COMP(ao0, ao1, ao2, ao3, bo0, bo1, bo2, bo3, bo4, bo5, bo6, bo7);   // t = 33

  // epilogue: scale by x0[row, a], atomic-accumulate into out
  int jrow = (lane >> 4) * 4;
  int r15 = lane & 15;
#pragma unroll
  for (int mi = 0; mi < 2; ++mi) {
#pragma unroll
    for (int j = 0; j < 4; ++j) {
      int row = n0 + wr * 32 + mi * 16 + jrow + j;
      float s = x0[(size_t)row * DIM0 + a];
#pragma unroll
      for (int ni = 0; ni < 4; ++ni) {
        int col = wc * 64 + ni * 16 + r15;
        atomicAdd(&out[(size_t)row * OO + col], acc[mi][ni][j] * s);
      }
    }
  }
}

// ---- bias + relu, in place on d_out ----
__global__ __launch_bounds__(256) void relu_kernel(float* __restrict__ out,
                                                   const float* __restrict__ bias) {
  int i = blockIdx.x * 256 + threadIdx.x;
  out[i] = fmaxf(out[i] + bias[i & (OO - 1)], 0.f);
}

extern "C" void kernel_launch(void* const* d_in, const int* in_sizes, int n_in,
                              void* d_out, int out_size, void* d_ws, size_t ws_size,
                              hipStream_t stream) {
  const float* x0   = (const float*)d_in[0];
  const float* x1   = (const float*)d_in[1];
  const float* x2   = (const float*)d_in[2];
  const float* W    = (const float*)d_in[3];
  const float* bias = (const float*)d_in[4];
  float* out = (float*)d_out;

  ushort* Uf  = (ushort*)d_ws;                                  // 32*34*8*512*2  = 8,912,896 B
  ushort* Wtf = (ushort*)((char*)d_ws + (size_t)8912896);       // 33*34*16*512*2 = 18,382,848 B

  hipMemsetAsync(d_out, 0, (size_t)NROW * OO * sizeof(float), stream);
  prep_u_kernel<<<dim3(32, 34), 256, 0, stream>>>(x1, x2, Uf);
  prep_wt_kernel<<<dim3(34, 33), 256, 0, stream>>>(W, Wtf);
  gemm_kernel<<<1056, 256, 0, stream>>>(Uf, Wtf, x0, out);
  relu_kernel<<<(NROW * OO) / 256, 256, 0, stream>>>(out, bias);
}

// Round 6
// 107.447 us; speedup vs baseline: 1.1158x; 1.1158x over previous
//
#include <hip/hip_runtime.h>
#include <hip/hip_bf16.h>

typedef __attribute__((ext_vector_type(8))) short bf16x8;
typedef __attribute__((ext_vector_type(4))) float f32x4;

#define U_LD 2176      // padded K (multiple of 64)
#define K_REAL 2145    // 33*65
#define NKT 34         // 2176/64
#define DIM0 33
#define DIM1 33
#define DIM2 65
#define NROW 2048
#define OO 128

__device__ __forceinline__ unsigned short f2bf(float f) {
  union { float f; unsigned u; } v; v.f = f;
  unsigned r = v.u + 0x7fffu + ((v.u >> 16) & 1u);   // round-to-nearest-even
  return (unsigned short)(r >> 16);
}

#define GLOAD_LDS16(SRC, DST) \
  __builtin_amdgcn_global_load_lds((const __attribute__((address_space(1))) void*)(SRC), \
                                   (__attribute__((address_space(3))) void*)(DST), 16, 0, 0)

// ---- U[n][k] = bf16( x1[n,b] * x2[n,c] ),  k = b*65+c, zero-padded to 2176 ----
__global__ __launch_bounds__(256) void prep_u_kernel(const float* __restrict__ x1,
                                                     const float* __restrict__ x2,
                                                     ushort* __restrict__ U) {
  __shared__ float s1[DIM1], s2[DIM2];
  int n = blockIdx.x;
  int tid = threadIdx.x;
  if (tid < DIM1) s1[tid] = x1[n * DIM1 + tid];
  int t2 = tid - DIM1;
  if (t2 >= 0 && t2 < DIM2) s2[t2] = x2[n * DIM2 + t2];
  __syncthreads();
  for (int k8 = tid; k8 < U_LD / 8; k8 += 256) {
    union { ushort us[8]; uint4 v; } pk;
#pragma unroll
    for (int j = 0; j < 8; ++j) {
      int k = k8 * 8 + j;
      float val = 0.f;
      if (k < K_REAL) { int b = k / DIM2; int c = k - b * DIM2; val = s1[b] * s2[c]; }
      pk.us[j] = f2bf(val);
    }
    *(uint4*)&U[(size_t)n * U_LD + k8 * 8] = pk.v;
  }
}

// ---- Wt[a][o][k] = bf16( W[a,b,c,o] ), k = b*65+c, zero-padded ----
__global__ __launch_bounds__(256) void prep_wt_kernel(const float* __restrict__ W,
                                                      ushort* __restrict__ Wt) {
  __shared__ ushort s[64][130];   // [k][o], pad to 130 to spread banks
  int a = blockIdx.y;
  int k0 = blockIdx.x * 64;       // 34 slabs of 64 k
  int tid = threadIdx.x;
  for (int idx = tid; idx < 64 * 32; idx += 256) {
    int kk = idx >> 5;
    int og = (idx & 31) * 4;
    int k = k0 + kk;
    float4 v = make_float4(0.f, 0.f, 0.f, 0.f);
    if (k < K_REAL) {
      int b = k / DIM2; int c = k - b * DIM2;
      v = *(const float4*)&W[(((size_t)a * DIM1 + b) * DIM2 + c) * OO + og];
    }
    s[kk][og]     = f2bf(v.x);
    s[kk][og + 1] = f2bf(v.y);
    s[kk][og + 2] = f2bf(v.z);
    s[kk][og + 3] = f2bf(v.w);
  }
  __syncthreads();
  int o  = tid >> 1;
  int kh = (tid & 1) * 32;
  union { ushort us[32]; uint4 v[4]; } pk;
#pragma unroll
  for (int j = 0; j < 32; ++j) pk.us[j] = s[kh + j][o];
  uint4* dst = (uint4*)&Wt[((size_t)a * OO + o) * U_LD + k0 + kh];
#pragma unroll
  for (int q = 0; q < 4; ++q) dst[q] = pk.v[q];
}

// ---- main GEMM: 64x128 tile, one a per block.
//      Triple-buffered LDS, prefetch distance 2, counted vmcnt(12) per phase:
//      issue-to-wait gap ~2 full phases, covering L2-miss/L3 latency. ----
__global__ __launch_bounds__(256) void gemm_kernel(const ushort* __restrict__ U,
                                                   const ushort* __restrict__ Wt,
                                                   const float* __restrict__ x0,
                                                   float* __restrict__ out) {
  // per buffer: A [64 rows][64 k] = 8KB (ushort 0..4095), B [128 o][64 k] = 16KB (4096..12287)
  __shared__ ushort lds[3][12288];   // 72 KB -> 2 blocks/CU

  int tid = threadIdx.x;
  int lane = tid & 63;
  int w = tid >> 6;
  int wr = w >> 1, wc = w & 1;

  // XCD-aware bijective swizzle: 1056 blocks, 132 per XCD, a-major within XCD.
  int orig = (int)blockIdx.x;
  int logical = (orig & 7) * 132 + (orig >> 3);
  int a = logical >> 5;        // 0..32
  int m = logical & 31;        // 0..31
  int n0 = m * 64;

  int kblk = lane >> 4;        // 0..3
  int r15 = lane & 15;
  int swz = lane & 7;

  f32x4 acc[2][4];
#pragma unroll
  for (int mi = 0; mi < 2; ++mi)
#pragma unroll
    for (int ni = 0; ni < 4; ++ni)
      acc[mi][ni] = (f32x4){0.f, 0.f, 0.f, 0.f};

  const ushort* WtA = Wt + (size_t)a * OO * U_LD;

  // --- per-thread staging constants: 6 chunks, pointer-bumped (+64 ushorts/step) ---
  int c0 = tid;        int rA0 = c0 >> 3;  int dA0 = c0 * 8;
  int c1 = 256 + tid;  int rA1 = c1 >> 3;  int dA1 = c1 * 8;
  const ushort* pA0 = U + (size_t)(n0 + rA0) * U_LD + ((c0 & 7) ^ (rA0 & 7)) * 8;
  const ushort* pA1 = U + (size_t)(n0 + rA1) * U_LD + ((c1 & 7) ^ (rA1 & 7)) * 8;
  int cB0 = tid;        int rB0 = cB0 >> 3;  int dB0 = 4096 + cB0 * 8;
  int cB1 = 256 + tid;  int rB1 = cB1 >> 3;  int dB1 = 4096 + cB1 * 8;
  int cB2 = 512 + tid;  int rB2 = cB2 >> 3;  int dB2 = 4096 + cB2 * 8;
  int cB3 = 768 + tid;  int rB3 = cB3 >> 3;  int dB3 = 4096 + cB3 * 8;
  const ushort* pB0 = WtA + (size_t)rB0 * U_LD + ((cB0 & 7) ^ (rB0 & 7)) * 8;
  const ushort* pB1 = WtA + (size_t)rB1 * U_LD + ((cB1 & 7) ^ (rB1 & 7)) * 8;
  const ushort* pB2 = WtA + (size_t)rB2 * U_LD + ((cB2 & 7) ^ (rB2 & 7)) * 8;
  const ushort* pB3 = WtA + (size_t)rB3 * U_LD + ((cB3 & 7) ^ (rB3 & 7)) * 8;

  auto STAGE = [&](ushort* Lb) {
    GLOAD_LDS16(pA0, Lb + dA0); pA0 += 64;
    GLOAD_LDS16(pA1, Lb + dA1); pA1 += 64;
    GLOAD_LDS16(pB0, Lb + dB0); pB0 += 64;
    GLOAD_LDS16(pB1, Lb + dB1); pB1 += 64;
    GLOAD_LDS16(pB2, Lb + dB2); pB2 += 64;
    GLOAD_LDS16(pB3, Lb + dB3); pB3 += 64;
  };

  auto COMPUTE = [&](const ushort* Lb) {
    const char* base = (const char*)Lb;
#pragma unroll
    for (int ks = 0; ks < 2; ++ks) {
      bf16x8 af[2], bfr[4];
#pragma unroll
      for (int mi = 0; mi < 2; ++mi) {
        int off = (wr * 32 + mi * 16 + r15) * 128 + ((((ks * 4) + kblk) ^ swz) << 4);
        af[mi] = *(const bf16x8*)(base + off);
      }
#pragma unroll
      for (int ni = 0; ni < 4; ++ni) {
        int off = 8192 + (wc * 64 + ni * 16 + r15) * 128 + ((((ks * 4) + kblk) ^ swz) << 4);
        bfr[ni] = *(const bf16x8*)(base + off);
      }
      __builtin_amdgcn_s_setprio(1);
#pragma unroll
      for (int mi = 0; mi < 2; ++mi)
#pragma unroll
        for (int ni = 0; ni < 4; ++ni)
          acc[mi][ni] = __builtin_amdgcn_mfma_f32_16x16x32_bf16(af[mi], bfr[ni], acc[mi][ni], 0, 0, 0);
      __builtin_amdgcn_s_setprio(0);
    }
  };

  // prologue: tiles 0,1,2 in flight (18 loads); wait tile 0 only (18-12=6 oldest)
  STAGE(&lds[0][0]);
  STAGE(&lds[1][0]);
  STAGE(&lds[2][0]);
  asm volatile("s_waitcnt vmcnt(12)" ::: "memory");
  __builtin_amdgcn_s_barrier();

  // steady state: per phase t (buffer t%3): COMPUTE(t); barrier (readers done);
  // STAGE(t+3 into same buffer); vmcnt(12) => t+1 landed (t+2,t+3 in flight); barrier.
#define PHASE_FULL(B) \
    COMPUTE(&lds[B][0]); \
    __builtin_amdgcn_s_barrier(); \
    STAGE(&lds[B][0]); \
    asm volatile("s_waitcnt vmcnt(12)" ::: "memory"); \
    __builtin_amdgcn_s_barrier();

  for (int it = 0; it < 10; ++it) {   // t = 0..29, staging tiles 3..32
    PHASE_FULL(0)
    PHASE_FULL(1)
    PHASE_FULL(2)
  }
  PHASE_FULL(0)                       // t=30, stages tile 33 (the last); t=31 landed
  // t=31: no more stages; outstanding = tiles 32,33 (12 loads) -> wait 6 => t=32 landed
  COMPUTE(&lds[1][0]);
  __builtin_amdgcn_s_barrier();
  asm volatile("s_waitcnt vmcnt(6)" ::: "memory");
  __builtin_amdgcn_s_barrier();
  // t=32: wait 0 => tile 33 landed
  COMPUTE(&lds[2][0]);
  __builtin_amdgcn_s_barrier();
  asm volatile("s_waitcnt vmcnt(0)" ::: "memory");
  __builtin_amdgcn_s_barrier();
  // t=33
  COMPUTE(&lds[0][0]);

  // epilogue: scale by x0[row, a], atomic-accumulate into out
  int jrow = (lane >> 4) * 4;
#pragma unroll
  for (int mi = 0; mi < 2; ++mi) {
#pragma unroll
    for (int j = 0; j < 4; ++j) {
      int row = n0 + wr * 32 + mi * 16 + jrow + j;
      float s = x0[(size_t)row * DIM0 + a];
#pragma unroll
      for (int ni = 0; ni < 4; ++ni) {
        int col = wc * 64 + ni * 16 + r15;
        atomicAdd(&out[(size_t)row * OO + col], acc[mi][ni][j] * s);
      }
    }
  }
}

// ---- bias + relu, in place on d_out ----
__global__ __launch_bounds__(256) void relu_kernel(float* __restrict__ out,
                                                   const float* __restrict__ bias) {
  int i = blockIdx.x * 256 + threadIdx.x;
  out[i] = fmaxf(out[i] + bias[i & (OO - 1)], 0.f);
}

extern "C" void kernel_launch(void* const* d_in, const int* in_sizes, int n_in,
                              void* d_out, int out_size, void* d_ws, size_t ws_size,
                              hipStream_t stream) {
  const float* x0   = (const float*)d_in[0];
  const float* x1   = (const float*)d_in[1];
  const float* x2   = (const float*)d_in[2];
  const float* W    = (const float*)d_in[3];
  const float* bias = (const float*)d_in[4];
  float* out = (float*)d_out;

  ushort* U  = (ushort*)d_ws;                                   // 2048*2176*2 = 8,912,896 B
  ushort* Wt = (ushort*)((char*)d_ws + (size_t)8912896);        // 33*128*2176*2 = 18,382,848 B

  hipMemsetAsync(d_out, 0, (size_t)NROW * OO * sizeof(float), stream);
  prep_u_kernel<<<NROW, 256, 0, stream>>>(x1, x2, U);
  prep_wt_kernel<<<dim3(34, 33), 256, 0, stream>>>(W, Wt);
  gemm_kernel<<<1056, 256, 0, stream>>>(U, Wt, x0, out);
  relu_kernel<<<(NROW * OO) / 256, 256, 0, stream>>>(out, bias);
}